// Round 19
// baseline (2163.601 us; speedup 1.0000x reference)
//
#include <hip/hip_runtime.h>

// RNN: B=32, T=2048, E=256, H=256, L=2, f32 in/out, f16 dot core.
// Pipeline: proj0 -> ws.A (512 blocks); mega 96 blocks co-resident:
//   blk 0-15   L0 PAIRED scans (batches 2k,2k+1 in ONE instruction stream)
//   blk 16-79  chasers (2/batch, own blocks/barriers — r17 structure)
//   blk 80-95  L1 PAIRED scans: wait chunkdone(both) -> d_out + final ht
//
// v19 = r17 core + ILP batch-pairing. r18's TLP failed: shared block barrier
// forced the two batches into lockstep (synchronized stalls can't hide each
// other). v19 instead interleaves TWO independent recurrences inside one
// wave's instruction stream — they share the SAME weights (same layer), so
// wp[128] is loaded once; batch A's serial tail (last fdot2 chain->bfly->
// tanh->write, ~300cy exposed at 1 wave/SIMD in r17) overlaps with batch B's
// independent fdot2 issue. 256 thr, launch_bounds(256,1) => 512-VGPR budget,
// demand ~280.
// Core (r17-proven): thread (jg=tid>>2, p=tid&3) partials 4 cols {jg+64c}
// over i-quarter [64p,64p+64): 8 ds_read_b128/batch, 128 fdot2/batch, 2 DPP
// quad butterflies/col, static col select. LDS f16 quarter-stride-144B.
// Weights full-unroll packed f16x2 + KEEPALIVE (r15/r16 lessons).
// Sync (r13-proven): publisher __syncthreads + release store; consumer
// RELAXED poll + one acquire fence per chunk. Scan barrier LDS-only.

typedef _Float16 half2_t __attribute__((ext_vector_type(2)));

#define TT 2048
#define BB 32
#define XPB 8
#define CHUNK 64
#define NCHUNK (TT / CHUNK)  // 32

__device__ __forceinline__ unsigned packw(float lo, float hi) {
    half2_t r;
    r.x = (_Float16)lo;
    r.y = (_Float16)hi;
    return __builtin_bit_cast(unsigned, r);
}
#define H2(X) __builtin_bit_cast(half2_t, (X))

#define LDS_BARRIER() asm volatile("s_waitcnt lgkmcnt(0)\n\ts_barrier" ::: "memory")

__device__ __forceinline__ int rload(int* pf) {
    return __hip_atomic_load(pf, __ATOMIC_RELAXED, __HIP_MEMORY_SCOPE_AGENT);
}
__device__ __forceinline__ void astore(int* pf, int v) {
    __hip_atomic_store(pf, v, __ATOMIC_RELEASE, __HIP_MEMORY_SCOPE_AGENT);
}
#define ACQUIRE_FENCE() __builtin_amdgcn_fence(__ATOMIC_ACQUIRE, "agent")

// pin the 128 packed weights in arch VGPRs (r13/r16-proven)
#define KAW8(B)                                                             \
    "+v"(wp[(B)]), "+v"(wp[(B) + 1]), "+v"(wp[(B) + 2]), "+v"(wp[(B) + 3]), \
    "+v"(wp[(B) + 4]), "+v"(wp[(B) + 5]), "+v"(wp[(B) + 6]), "+v"(wp[(B) + 7])
#define KEEPALIVE()                                                  \
    asm volatile("" : KAW8(0), KAW8(8), KAW8(16), KAW8(24));         \
    asm volatile("" : KAW8(32), KAW8(40), KAW8(48), KAW8(56));       \
    asm volatile("" : KAW8(64), KAW8(72), KAW8(80), KAW8(88));       \
    asm volatile("" : KAW8(96), KAW8(104), KAW8(112), KAW8(120));

#define FDOTN(H, W_, A) A = __builtin_amdgcn_fdot2(H2(H), H2(W_), A, false)
#define FD4N(H, K, a0, a1, a2, a3)   \
    FDOTN(H, wp[(K)], a0);           \
    FDOTN(H, wp[32 + (K)], a1);      \
    FDOTN(H, wp[64 + (K)], a2);      \
    FDOTN(H, wp[96 + (K)], a3);

// partial dot over this lane's i-quarter, named accumulators
#define DOTSN(HBQ, a0, a1, a2, a3)                                       \
    {                                                                    \
        const uint4* hp_ = (HBQ) + 9 * p;                                \
        uint4 q0 = hp_[0], q1 = hp_[1], q2 = hp_[2], q3 = hp_[3];        \
        uint4 q4 = hp_[4], q5 = hp_[5], q6 = hp_[6], q7 = hp_[7];        \
        FD4N(q0.x, 0, a0, a1, a2, a3)  FD4N(q0.y, 1, a0, a1, a2, a3)     \
        FD4N(q0.z, 2, a0, a1, a2, a3)  FD4N(q0.w, 3, a0, a1, a2, a3)     \
        FD4N(q1.x, 4, a0, a1, a2, a3)  FD4N(q1.y, 5, a0, a1, a2, a3)     \
        FD4N(q1.z, 6, a0, a1, a2, a3)  FD4N(q1.w, 7, a0, a1, a2, a3)     \
        FD4N(q2.x, 8, a0, a1, a2, a3)  FD4N(q2.y, 9, a0, a1, a2, a3)     \
        FD4N(q2.z, 10, a0, a1, a2, a3) FD4N(q2.w, 11, a0, a1, a2, a3)    \
        FD4N(q3.x, 12, a0, a1, a2, a3) FD4N(q3.y, 13, a0, a1, a2, a3)    \
        FD4N(q3.z, 14, a0, a1, a2, a3) FD4N(q3.w, 15, a0, a1, a2, a3)    \
        FD4N(q4.x, 16, a0, a1, a2, a3) FD4N(q4.y, 17, a0, a1, a2, a3)    \
        FD4N(q4.z, 18, a0, a1, a2, a3) FD4N(q4.w, 19, a0, a1, a2, a3)    \
        FD4N(q5.x, 20, a0, a1, a2, a3) FD4N(q5.y, 21, a0, a1, a2, a3)    \
        FD4N(q5.z, 22, a0, a1, a2, a3) FD4N(q5.w, 23, a0, a1, a2, a3)    \
        FD4N(q6.x, 24, a0, a1, a2, a3) FD4N(q6.y, 25, a0, a1, a2, a3)    \
        FD4N(q6.z, 26, a0, a1, a2, a3) FD4N(q6.w, 27, a0, a1, a2, a3)    \
        FD4N(q7.x, 28, a0, a1, a2, a3) FD4N(q7.y, 29, a0, a1, a2, a3)    \
        FD4N(q7.z, 30, a0, a1, a2, a3) FD4N(q7.w, 31, a0, a1, a2, a3)    \
    }

// quad butterfly: x = sum over the 4 quad lanes (register-only, exact)
#define BFLY(x)                                                              \
    asm("v_add_f32_dpp %0, %0, %0 quad_perm:[1,0,3,2] row_mask:0xf "         \
        "bank_mask:0xf"                                                      \
        : "+v"(x));                                                          \
    asm("v_add_f32_dpp %0, %0, %0 quad_perm:[2,3,0,1] row_mask:0xf "         \
        "bank_mask:0xf"                                                      \
        : "+v"(x));

// load 128 packed weights (FULL unroll — r15 scratch lesson)
#define LOAD_WP4(Wm, rowbase, p_, jg_)                                       \
    _Pragma("unroll")                                                        \
    for (int c = 0; c < 4; ++c) {                                            \
        _Pragma("unroll")                                                    \
        for (int k = 0; k < 32; ++k) {                                       \
            const int col_ = (jg_) + 64 * c;                                 \
            wp[c * 32 + k] =                                                 \
                packw((Wm)[(size_t)((rowbase) + 64 * (p_) + 2 * k) * 256 +   \
                           col_],                                            \
                      (Wm)[(size_t)((rowbase) + 64 * (p_) + 2 * k + 1) * 256 \
                           + col_]);                                         \
        }                                                                    \
    }

// f16 staging index for element i (quarter stride 72 f16 = 144 B)
__device__ __forceinline__ int sidx_of(int i) {
    return 72 * (i >> 6) + (i & 63);
}

// proj rows (r17/r18-proven). ALIAS: per-row vmcnt drain for in-place.
template <bool ALIAS>
__device__ __forceinline__ void proj_rows(
    const float* __restrict__ src, float* __restrict__ dst,
    unsigned (&wp)[128], float bj, int nrows, uint4 (*hb)[36], int tid,
    int p, int jg, int col)
{
    _Float16* st0 = reinterpret_cast<_Float16*>(hb[0]);
    _Float16* st1 = reinterpret_cast<_Float16*>(hb[1]);
    const int si = sidx_of(tid);
    st0[si] = (_Float16)src[tid];
    __syncthreads();
    for (int r = 0; r < nrows; ++r) {
        KEEPALIVE()
        _Float16* stn = (r & 1) ? st0 : st1;
        if (r + 1 < nrows) stn[si] = (_Float16)src[(size_t)(r + 1) * 256 + tid];
        const uint4* hbq = hb[r & 1];
        float ac0 = 0.f, ac1 = 0.f, ac2 = 0.f, ac3 = 0.f;
        DOTSN(hbq, ac0, ac1, ac2, ac3)
        BFLY(ac0) BFLY(ac1) BFLY(ac2) BFLY(ac3)
        float z = (p == 0) ? ac0 : ((p == 1) ? ac1 : ((p == 2) ? ac2 : ac3));
        dst[(size_t)r * 256 + col] = z + bj;
        if (ALIAS) __syncthreads();
        else LDS_BARRIER();
    }
}

// PAIRED scan: one 256-thr block runs batches A and B (same layer => same
// weights) interleaved in one instruction stream.
// MODE: 0 = serial, 1 = L0 (publish), 2 = L1 (wait)
template <int MODE>
__device__ __forceinline__ void scan_pair(
    const float* __restrict__ W,
    const float* __restrict__ hiA, const float* __restrict__ hiB,
    const float* __restrict__ xsA, const float* __restrict__ xsB,
    float* __restrict__ hdA, float* __restrict__ hdB,
    float* hfA, float* hfB, int* pubA, int* pubB, int* wfA, int* wfB,
    uint4 (*hbb)[2][36], int tid)
{
    const int p = tid & 3;
    const int jg = tid >> 2;
    const int col = jg + 64 * p;

    unsigned wp[128];
    LOAD_WP4(W, 256, p, jg)

    reinterpret_cast<_Float16*>(hbb[0][0])[sidx_of(tid)] = (_Float16)hiA[tid];
    reinterpret_cast<_Float16*>(hbb[1][0])[sidx_of(tid)] = (_Float16)hiB[tid];
    const int wsi = 72 * p + jg;

    float xcA[XPB], xnA[XPB], hsA[XPB];
    float xcB[XPB], xnB[XPB], hsB[XPB];

    auto step = [&](int t, float xpA, float xpB, float& oA, float& oB) {
        KEEPALIVE()
        float aA0 = 0.f, aA1 = 0.f, aA2 = 0.f, aA3 = 0.f;
        float aB0 = 0.f, aB1 = 0.f, aB2 = 0.f, aB3 = 0.f;
        DOTSN(hbb[0][t & 1], aA0, aA1, aA2, aA3)
        DOTSN(hbb[1][t & 1], aB0, aB1, aB2, aB3)
        BFLY(aA0) BFLY(aA1) BFLY(aA2) BFLY(aA3)
        BFLY(aB0) BFLY(aB1) BFLY(aB2) BFLY(aB3)
        float zA = (p == 0) ? aA0 : ((p == 1) ? aA1 : ((p == 2) ? aA2 : aA3));
        float zB = (p == 0) ? aB0 : ((p == 1) ? aB1 : ((p == 2) ? aB2 : aB3));
        zA += xpA;
        zB += xpB;
        const float eA = __expf(2.0f * zA);
        const float eB = __expf(2.0f * zB);
        const float hA = 1.0f - 2.0f / (eA + 1.0f);
        const float hB = 1.0f - 2.0f / (eB + 1.0f);
        reinterpret_cast<_Float16*>(hbb[0][(t + 1) & 1])[wsi] = (_Float16)hA;
        reinterpret_cast<_Float16*>(hbb[1][(t + 1) & 1])[wsi] = (_Float16)hB;
        LDS_BARRIER();
        oA = hA;
        oB = hB;
    };

    if (MODE != 2) {
#pragma unroll
        for (int u = 0; u < XPB; ++u) {
            xcA[u] = xsA[(size_t)u * 256 + col];
            xcB[u] = xsB[(size_t)u * 256 + col];
        }
        __syncthreads();
        for (int t0 = 0; t0 < TT; t0 += XPB) {
            const bool more = (t0 + XPB) < TT;
            if (more) {
#pragma unroll
                for (int u = 0; u < XPB; ++u) {
                    xnA[u] = xsA[(size_t)(t0 + XPB + u) * 256 + col];
                    xnB[u] = xsB[(size_t)(t0 + XPB + u) * 256 + col];
                }
            }
#pragma unroll
            for (int u = 0; u < XPB; ++u)
                step(t0 + u, xcA[u], xcB[u], hsA[u], hsB[u]);
#pragma unroll
            for (int u = 0; u < XPB; ++u) {
                hdA[(size_t)(t0 + u) * 256 + col] = hsA[u];
                hdB[(size_t)(t0 + u) * 256 + col] = hsB[u];
            }
            if (MODE == 1 && (((t0 + XPB) & (CHUNK - 1)) == 0)) {
                __syncthreads();  // drain vmcnt (h stores) before release
                if (tid == 0) {
                    astore(pubA, t0 + XPB);
                    astore(pubB, t0 + XPB);
                }
            }
            if (more) {
#pragma unroll
                for (int u = 0; u < XPB; ++u) {
                    xcA[u] = xnA[u];
                    xcB[u] = xnB[u];
                }
            }
        }
        if (MODE == 0 && hfA != nullptr) {
            hfA[col] = hsA[XPB - 1];
            hfB[col] = hsB[XPB - 1];
        }
    } else {
        __syncthreads();
        for (int chunk = 0; chunk < NCHUNK; ++chunk) {
            const int tbase = chunk * CHUNK;
            while (rload(&wfA[chunk]) == 0 || rload(&wfB[chunk]) == 0)
                __builtin_amdgcn_s_sleep(1);
            ACQUIRE_FENCE();  // one inv per chunk
#pragma unroll
            for (int u = 0; u < XPB; ++u) {
                xcA[u] = xsA[(size_t)(tbase + u) * 256 + col];
                xcB[u] = xsB[(size_t)(tbase + u) * 256 + col];
            }
            for (int g = 0; g < CHUNK / XPB; ++g) {
                const int t0 = tbase + g * XPB;
                if (g + 1 < CHUNK / XPB) {
#pragma unroll
                    for (int u = 0; u < XPB; ++u) {
                        xnA[u] = xsA[(size_t)(t0 + XPB + u) * 256 + col];
                        xnB[u] = xsB[(size_t)(t0 + XPB + u) * 256 + col];
                    }
                }
#pragma unroll
                for (int u = 0; u < XPB; ++u)
                    step(t0 + u, xcA[u], xcB[u], hsA[u], hsB[u]);
#pragma unroll
                for (int u = 0; u < XPB; ++u) {
                    hdA[(size_t)(t0 + u) * 256 + col] = hsA[u];
                    hdB[(size_t)(t0 + u) * 256 + col] = hsB[u];
                }
                if (t0 + XPB == TT) {
                    hfA[col] = hsA[XPB - 1];
                    hfB[col] = hsB[XPB - 1];
                }
                if (g + 1 < CHUNK / XPB) {
#pragma unroll
                    for (int u = 0; u < XPB; ++u) {
                        xcA[u] = xnA[u];
                        xcB[u] = xnB[u];
                    }
                }
            }
        }
    }
}

// standalone proj
template <bool ALIAS>
__global__ __launch_bounds__(256, 1) void proj19_kernel(
    const float* in, const float* __restrict__ W, const float* __restrict__ bias,
    float* out, int rows_per_wg)
{
    __shared__ uint4 hb[2][36];
    const int tid = threadIdx.x;
    const int p = tid & 3;
    const int jg = tid >> 2;
    const int col = jg + 64 * p;
    unsigned wp[128];
    LOAD_WP4(W, 0, p, jg)
    const float bj = bias[col];
    const size_t r0 = (size_t)blockIdx.x * rows_per_wg;
    proj_rows<ALIAS>(in + r0 * 256, out + r0 * 256, wp, bj, rows_per_wg, hb,
                     tid, p, jg, col);
}

// serial fallback scan (paired, 16 blocks per layer)
__global__ __launch_bounds__(256, 1) void scan19_kernel(
    const float* __restrict__ W, const float* __restrict__ h_init,
    float* __restrict__ io, float* __restrict__ hfinal)
{
    __shared__ uint4 hbb[2][2][36];
    const int b0 = blockIdx.x * 2;
    scan_pair<0>(W, h_init + b0 * 256, h_init + (b0 + 1) * 256,
                 io + (size_t)b0 * TT * 256, io + (size_t)(b0 + 1) * TT * 256,
                 io + (size_t)b0 * TT * 256, io + (size_t)(b0 + 1) * TT * 256,
                 hfinal ? hfinal + b0 * 256 : nullptr,
                 hfinal ? hfinal + (b0 + 1) * 256 : nullptr,
                 nullptr, nullptr, nullptr, nullptr, hbb, threadIdx.x);
}

// mega: 96 blocks x 256 threads
__global__ __launch_bounds__(256, 1) void mega19_kernel(
    const float* __restrict__ W0, const float* __restrict__ W1,
    const float* __restrict__ b1v, const float* __restrict__ h0init,
    float* xpA, float* out, int* flags)
{
    const int tid = threadIdx.x;
    const int bid = blockIdx.x;
    int* flagL0 = flags;               // stride 16 ints per batch (64B line)
    int* chunkdone = flags + BB * 16;  // stride NCHUNK ints per batch

    if (bid < 16 || bid >= 80) {
        __shared__ uint4 hbb[2][2][36];
        if (bid < 16) {
            // ---- L0 paired scans ----
            const int b0 = bid * 2;
            scan_pair<1>(W0, h0init + b0 * 256, h0init + (b0 + 1) * 256,
                         xpA + (size_t)b0 * TT * 256,
                         xpA + (size_t)(b0 + 1) * TT * 256,
                         out + (size_t)b0 * TT * 256,
                         out + (size_t)(b0 + 1) * TT * 256, nullptr, nullptr,
                         &flagL0[b0 * 16], &flagL0[(b0 + 1) * 16], nullptr,
                         nullptr, hbb, tid);
        } else {
            // ---- L1 paired scans ----
            const int b0 = (bid - 80) * 2;
            scan_pair<2>(W1, h0init + (size_t)(BB + b0) * 256,
                         h0init + (size_t)(BB + b0 + 1) * 256,
                         xpA + (size_t)b0 * TT * 256,
                         xpA + (size_t)(b0 + 1) * TT * 256,
                         out + (size_t)b0 * TT * 256,
                         out + (size_t)(b0 + 1) * TT * 256,
                         out + (size_t)BB * TT * 256 + b0 * 256,
                         out + (size_t)BB * TT * 256 + (b0 + 1) * 256,
                         nullptr, nullptr, &chunkdone[b0 * NCHUNK],
                         &chunkdone[(b0 + 1) * NCHUNK], hbb, tid);
        }
    } else {
        // ---- proj1 chasers (2/batch, own blocks — r17 structure) ----
        __shared__ uint4 hb[2][36];
        const int k = bid - 16;  // 0..63
        const int b = k >> 1;
        const int half = k & 1;
        const int p = tid & 3;
        const int jg = tid >> 2;
        const int col = jg + 64 * p;

        unsigned wp[128];
        LOAD_WP4(W1, 0, p, jg)
        const float bj = b1v[col];

        for (int chunk = half; chunk < NCHUNK; chunk += 2) {
            while (rload(&flagL0[b * 16]) < (chunk + 1) * CHUNK)
                __builtin_amdgcn_s_sleep(1);
            ACQUIRE_FENCE();  // one inv per chunk
            const int tbase = chunk * CHUNK;
            const float* src = out + ((size_t)b * TT + tbase) * 256;  // h0 rows
            float* dst = xpA + ((size_t)b * TT + tbase) * 256;        // xproj1
            proj_rows<false>(src, dst, wp, bj, CHUNK, hb, tid, p, jg, col);
            __syncthreads();  // drain vmcnt (dst stores) before release
            if (tid == 0) astore(&chunkdone[b * NCHUNK + chunk], 1);
        }
    }
}

extern "C" void kernel_launch(void* const* d_in, const int* in_sizes, int n_in,
                              void* d_out, int out_size, void* d_ws, size_t ws_size,
                              hipStream_t stream) {
    const float* x  = (const float*)d_in[0];  // [B,T,256]
    const float* h0 = (const float*)d_in[1];  // [2,B,256]
    const float* W0 = (const float*)d_in[2];  // [512,256]
    const float* b0 = (const float*)d_in[3];  // [256]
    const float* W1 = (const float*)d_in[4];  // [512,256]
    const float* b1 = (const float*)d_in[5];  // [256]
    float* out = (float*)d_out;               // [B*T*256] + [B*256]

    const size_t XPA_FLOATS = (size_t)BB * TT * 256;  // 64 MB
    const size_t FLAG_INTS = (size_t)BB * 16 + (size_t)BB * NCHUNK;
    const size_t NEEDED = XPA_FLOATS * 4 + FLAG_INTS * 4;

    if (ws_size >= NEEDED) {
        float* xpA = (float*)d_ws;
        int* flags = (int*)((char*)d_ws + XPA_FLOATS * 4);
        hipMemsetAsync(flags, 0, FLAG_INTS * 4, stream);
        proj19_kernel<false><<<512, 256, 0, stream>>>(x, W0, b0, xpA, 128);
        mega19_kernel<<<96, 256, 0, stream>>>(W0, W1, b1, h0, xpA, out, flags);
    } else {
        proj19_kernel<true><<<512, 256, 0, stream>>>(x, W0, b0, out, 128);
        scan19_kernel<<<16, 256, 0, stream>>>(W0, h0, out, nullptr);
        proj19_kernel<true><<<512, 256, 0, stream>>>(out, W1, b1, out, 128);
        scan19_kernel<<<16, 256, 0, stream>>>(W1, h0 + BB * 256, out,
                                              out + XPA_FLOATS);
    }
}

// Round 20
// 1417.134 us; speedup vs baseline: 1.5267x; 1.5267x over previous
//
#include <hip/hip_runtime.h>

// RNN: B=32, T=2048, E=256, H=256, L=2, f32 in/out, f16 dot core.
// Pipeline: proj0 -> ws.A (512 blocks); mega GRID 512 (co-residency pairing):
//   bid 0-31    L0 scan batch b          (slot0 of CU b per round-robin model)
//   bid 32-63   L1 scan batch b-32
//   bid 256-287 chaser (b-256, parity 0) -> slot1 of L0 b's CU
//   bid 288-319 chaser (b-288, parity 1) -> slot1 of L1 b's CU
//   bid 64-255, 320-511: exit immediately.
// v20 = r17 (best, 1280us) + pairing. r17 left every CU at 1 wave/SIMD with
// ~650cy/step naked latency stall and half the GPU idle. Dispatcher model:
// XCD=bid%8, CU=(bid/8)%32, slot=(bid/8)/32 => bid k and k+256 co-locate.
// Paired CU: scan wave + chaser wave per SIMD — chaser issue (~160cy/step)
// fills scan stalls; separate blocks => separate barriers (no r18 lockstep),
// separate regalloc (128+128 <= 512/SIMD; launch_bounds(256,2)). All 512
// blocks co-resident (256 CUs x 2) => no deadlock; wrong model => exactly
// r17 perf (placement is a perf-only heuristic).
// Core (r17-proven): thread (jg=tid>>2, p=tid&3) partials 4 cols {jg+64c}
// over i-quarter [64p,64p+64): 8 ds_read_b128, 128 fdot2, 2 DPP quad
// butterflies/col, static col select. LDS f16 quarter-stride-144B.
// Weights: 128 packed f16x2 VGPRs (full unroll + unsigned + KEEPALIVE).
// Sync (r13-proven): publisher __syncthreads + release store; consumer
// RELAXED poll + one acquire fence per chunk. Scan barrier LDS-only.

typedef _Float16 half2_t __attribute__((ext_vector_type(2)));

#define TT 2048
#define BB 32
#define XPB 8
#define CHUNK 64
#define NCHUNK (TT / CHUNK)  // 32

__device__ __forceinline__ unsigned packw(float lo, float hi) {
    half2_t r;
    r.x = (_Float16)lo;
    r.y = (_Float16)hi;
    return __builtin_bit_cast(unsigned, r);
}
#define H2(X) __builtin_bit_cast(half2_t, (X))

#define LDS_BARRIER() asm volatile("s_waitcnt lgkmcnt(0)\n\ts_barrier" ::: "memory")

__device__ __forceinline__ int rload(int* pf) {
    return __hip_atomic_load(pf, __ATOMIC_RELAXED, __HIP_MEMORY_SCOPE_AGENT);
}
__device__ __forceinline__ void astore(int* pf, int v) {
    __hip_atomic_store(pf, v, __ATOMIC_RELEASE, __HIP_MEMORY_SCOPE_AGENT);
}
#define ACQUIRE_FENCE() __builtin_amdgcn_fence(__ATOMIC_ACQUIRE, "agent")

// r13/r16-proven keep-alive: pin the 128 packed weights in arch VGPRs
#define KAW8(B)                                                             \
    "+v"(wp[(B)]), "+v"(wp[(B) + 1]), "+v"(wp[(B) + 2]), "+v"(wp[(B) + 3]), \
    "+v"(wp[(B) + 4]), "+v"(wp[(B) + 5]), "+v"(wp[(B) + 6]), "+v"(wp[(B) + 7])
#define KEEPALIVE()                                                  \
    asm volatile("" : KAW8(0), KAW8(8), KAW8(16), KAW8(24));         \
    asm volatile("" : KAW8(32), KAW8(40), KAW8(48), KAW8(56));       \
    asm volatile("" : KAW8(64), KAW8(72), KAW8(80), KAW8(88));       \
    asm volatile("" : KAW8(96), KAW8(104), KAW8(112), KAW8(120));

#define FDOT(H, W_, A) A = __builtin_amdgcn_fdot2(H2(H), H2(W_), A, false)
#define FD4(H, K)               \
    FDOT(H, wp[(K)], ac0);      \
    FDOT(H, wp[32 + (K)], ac1); \
    FDOT(H, wp[64 + (K)], ac2); \
    FDOT(H, wp[96 + (K)], ac3);

// partial dot over this lane's i-quarter for its 4 columns.
#define DOTS()                                                          \
    float ac0 = 0.f, ac1 = 0.f, ac2 = 0.f, ac3 = 0.f;                   \
    {                                                                   \
        const uint4* hp_ = hbq + 9 * p;                                 \
        uint4 q0 = hp_[0], q1 = hp_[1], q2 = hp_[2], q3 = hp_[3];       \
        uint4 q4 = hp_[4], q5 = hp_[5], q6 = hp_[6], q7 = hp_[7];       \
        FD4(q0.x, 0)  FD4(q0.y, 1)  FD4(q0.z, 2)  FD4(q0.w, 3)         \
        FD4(q1.x, 4)  FD4(q1.y, 5)  FD4(q1.z, 6)  FD4(q1.w, 7)         \
        FD4(q2.x, 8)  FD4(q2.y, 9)  FD4(q2.z, 10) FD4(q2.w, 11)        \
        FD4(q3.x, 12) FD4(q3.y, 13) FD4(q3.z, 14) FD4(q3.w, 15)        \
        FD4(q4.x, 16) FD4(q4.y, 17) FD4(q4.z, 18) FD4(q4.w, 19)        \
        FD4(q5.x, 20) FD4(q5.y, 21) FD4(q5.z, 22) FD4(q5.w, 23)        \
        FD4(q6.x, 24) FD4(q6.y, 25) FD4(q6.z, 26) FD4(q6.w, 27)        \
        FD4(q7.x, 28) FD4(q7.y, 29) FD4(q7.z, 30) FD4(q7.w, 31)        \
    }

// quad butterfly: x = sum over the 4 quad lanes (register-only, exact)
#define BFLY(x)                                                              \
    asm("v_add_f32_dpp %0, %0, %0 quad_perm:[1,0,3,2] row_mask:0xf "         \
        "bank_mask:0xf"                                                      \
        : "+v"(x));                                                          \
    asm("v_add_f32_dpp %0, %0, %0 quad_perm:[2,3,0,1] row_mask:0xf "         \
        "bank_mask:0xf"                                                      \
        : "+v"(x));

// load 128 packed weights (FULL unroll — r15 scratch lesson)
#define LOAD_WP4(Wm, rowbase, p_, jg_)                                       \
    _Pragma("unroll")                                                        \
    for (int c = 0; c < 4; ++c) {                                            \
        _Pragma("unroll")                                                    \
        for (int k = 0; k < 32; ++k) {                                       \
            const int col_ = (jg_) + 64 * c;                                 \
            wp[c * 32 + k] =                                                 \
                packw((Wm)[(size_t)((rowbase) + 64 * (p_) + 2 * k) * 256 +   \
                           col_],                                            \
                      (Wm)[(size_t)((rowbase) + 64 * (p_) + 2 * k + 1) * 256 \
                           + col_]);                                         \
        }                                                                    \
    }

// f16 staging index for element i (quarter stride 72 f16 = 144 B)
__device__ __forceinline__ int sidx_of(int i) {
    return 72 * (i >> 6) + (i & 63);
}

// proj rows: dst[r][col] = src[r][:] . W[:256][col] + b[col]
// ALIAS=true: in-place path, per-row full __syncthreads (vmcnt drain).
template <bool ALIAS>
__device__ __forceinline__ void proj_rows(
    const float* __restrict__ src, float* __restrict__ dst,
    unsigned (&wp)[128], float bj, int nrows, uint4 (*hb)[36], int tid,
    int p, int jg, int col)
{
    _Float16* st0 = reinterpret_cast<_Float16*>(hb[0]);
    _Float16* st1 = reinterpret_cast<_Float16*>(hb[1]);
    const int si = sidx_of(tid);
    st0[si] = (_Float16)src[tid];
    __syncthreads();
    for (int r = 0; r < nrows; ++r) {
        KEEPALIVE()
        _Float16* stn = (r & 1) ? st0 : st1;
        if (r + 1 < nrows) stn[si] = (_Float16)src[(size_t)(r + 1) * 256 + tid];
        const uint4* hbq = hb[r & 1];
        DOTS()
        BFLY(ac0) BFLY(ac1) BFLY(ac2) BFLY(ac3)
        float z = (p == 0) ? ac0 : ((p == 1) ? ac1 : ((p == 2) ? ac2 : ac3));
        dst[(size_t)r * 256 + col] = z + bj;
        if (ALIAS) __syncthreads();
        else LDS_BARRIER();
    }
}

// MODE: 0 = serial, 1 = L0 (publish pubflag), 2 = L1 (wait waitflags)
template <int MODE>
__device__ __forceinline__ void scan_core(
    const float* __restrict__ W, const float* __restrict__ h_init,
    const float* __restrict__ xsrc, float* __restrict__ hdst, float* hfinal,
    int* pubflag, int* waitflags, uint4 (*hb)[36], int tid)
{
    const int p = tid & 3;
    const int jg = tid >> 2;
    const int col = jg + 64 * p;

    unsigned wp[128];
    LOAD_WP4(W, 256, p, jg)

    _Float16* hw0 = reinterpret_cast<_Float16*>(hb[0]);
    _Float16* hw1 = reinterpret_cast<_Float16*>(hb[1]);
    hw0[sidx_of(tid)] = (_Float16)h_init[tid];
    const int wsi = 72 * p + jg;  // where this lane's column lives

    float xpc[XPB], xpn[XPB], hs[XPB];

    auto step = [&](int t, float xp) -> float {
        KEEPALIVE()
        const uint4* hbq = hb[t & 1];
        DOTS()
        BFLY(ac0) BFLY(ac1) BFLY(ac2) BFLY(ac3)
        float z = (p == 0) ? ac0 : ((p == 1) ? ac1 : ((p == 2) ? ac2 : ac3));
        z += xp;
        const float e = __expf(2.0f * z);
        const float hn = 1.0f - 2.0f / (e + 1.0f);
        _Float16* dstw = ((t + 1) & 1) ? hw1 : hw0;
        dstw[wsi] = (_Float16)hn;
        LDS_BARRIER();
        return hn;
    };

    if (MODE != 2) {
#pragma unroll
        for (int u = 0; u < XPB; ++u) xpc[u] = xsrc[(size_t)u * 256 + col];
        __syncthreads();
        for (int t0 = 0; t0 < TT; t0 += XPB) {
            const bool more = (t0 + XPB) < TT;
            if (more) {
#pragma unroll
                for (int u = 0; u < XPB; ++u)
                    xpn[u] = xsrc[(size_t)(t0 + XPB + u) * 256 + col];
            }
#pragma unroll
            for (int u = 0; u < XPB; ++u) hs[u] = step(t0 + u, xpc[u]);
#pragma unroll
            for (int u = 0; u < XPB; ++u)
                hdst[(size_t)(t0 + u) * 256 + col] = hs[u];
            if (MODE == 1 && (((t0 + XPB) & (CHUNK - 1)) == 0)) {
                __syncthreads();  // drain vmcnt (h stores) before release
                if (tid == 0) astore(pubflag, t0 + XPB);
            }
            if (more) {
#pragma unroll
                for (int u = 0; u < XPB; ++u) xpc[u] = xpn[u];
            }
        }
        if (MODE == 0 && hfinal != nullptr) hfinal[col] = hs[XPB - 1];
    } else {
        __syncthreads();
        for (int chunk = 0; chunk < NCHUNK; ++chunk) {
            const int tbase = chunk * CHUNK;
            while (rload(&waitflags[chunk]) == 0) __builtin_amdgcn_s_sleep(1);
            ACQUIRE_FENCE();  // one inv per chunk
#pragma unroll
            for (int u = 0; u < XPB; ++u)
                xpc[u] = xsrc[(size_t)(tbase + u) * 256 + col];
            for (int g = 0; g < CHUNK / XPB; ++g) {
                const int t0 = tbase + g * XPB;
                if (g + 1 < CHUNK / XPB) {
#pragma unroll
                    for (int u = 0; u < XPB; ++u)
                        xpn[u] = xsrc[(size_t)(t0 + XPB + u) * 256 + col];
                }
#pragma unroll
                for (int u = 0; u < XPB; ++u) hs[u] = step(t0 + u, xpc[u]);
#pragma unroll
                for (int u = 0; u < XPB; ++u)
                    hdst[(size_t)(t0 + u) * 256 + col] = hs[u];
                if (t0 + XPB == TT) hfinal[col] = hs[XPB - 1];
                if (g + 1 < CHUNK / XPB) {
#pragma unroll
                    for (int u = 0; u < XPB; ++u) xpc[u] = xpn[u];
                }
            }
        }
    }
}

// standalone proj
template <bool ALIAS>
__global__ __launch_bounds__(256, 1) void proj20_kernel(
    const float* in, const float* __restrict__ W, const float* __restrict__ bias,
    float* out, int rows_per_wg)
{
    __shared__ uint4 hb[2][36];
    const int tid = threadIdx.x;
    const int p = tid & 3;
    const int jg = tid >> 2;
    const int col = jg + 64 * p;
    unsigned wp[128];
    LOAD_WP4(W, 0, p, jg)
    const float bj = bias[col];
    const size_t r0 = (size_t)blockIdx.x * rows_per_wg;
    proj_rows<ALIAS>(in + r0 * 256, out + r0 * 256, wp, bj, rows_per_wg, hb,
                     tid, p, jg, col);
}

// serial fallback scan (single batch, 256 thr)
__global__ __launch_bounds__(256, 1) void scan20_kernel(
    const float* __restrict__ W, const float* __restrict__ h_init,
    float* __restrict__ io, float* __restrict__ hfinal)
{
    __shared__ uint4 hb[2][36];
    const int b = blockIdx.x;
    scan_core<0>(W, h_init + b * 256, io + (size_t)b * TT * 256,
                 io + (size_t)b * TT * 256,
                 hfinal ? hfinal + b * 256 : nullptr, nullptr, nullptr, hb,
                 threadIdx.x);
}

// mega: GRID 512, 256 thr; roles laid out so bid k and k+256 co-locate
// (XCD=bid%8, CU=(bid/8)%32, slot=(bid/8)/32 round-robin model).
__global__ __launch_bounds__(256, 2) void mega20_kernel(
    const float* __restrict__ W0, const float* __restrict__ W1,
    const float* __restrict__ b1v, const float* __restrict__ h0init,
    float* xpA, float* out, int* flags)
{
    const int tid = threadIdx.x;
    const int bid = blockIdx.x;
    int* flagL0 = flags;               // stride 16 ints per batch (64B line)
    int* chunkdone = flags + BB * 16;  // stride NCHUNK ints per batch

    if (bid < BB) {
        // ---- L0 scan, batch b ----
        __shared__ uint4 hb[2][36];
        const int b = bid;
        scan_core<1>(W0, h0init + b * 256, xpA + (size_t)b * TT * 256,
                     out + (size_t)b * TT * 256, nullptr, &flagL0[b * 16],
                     nullptr, hb, tid);
    } else if (bid < 2 * BB) {
        // ---- L1 scan, batch b ----
        __shared__ uint4 hb[2][36];
        const int b = bid - BB;
        scan_core<2>(W1, h0init + (size_t)(BB + b) * 256,
                     xpA + (size_t)b * TT * 256, out + (size_t)b * TT * 256,
                     out + (size_t)BB * TT * 256 + b * 256, nullptr,
                     &chunkdone[b * NCHUNK], hb, tid);
    } else if (bid >= 256 && bid < 256 + 2 * BB) {
        // ---- chasers: bid-256 in [0,32) parity 0 (pairs with L0 CU);
        //               bid-256 in [32,64) parity 1 (pairs with L1 CU) ----
        __shared__ uint4 hb[2][36];
        const int k = bid - 256;
        const int parity = (k < BB) ? 0 : 1;
        const int b = (k < BB) ? k : (k - BB);
        const int p = tid & 3;
        const int jg = tid >> 2;
        const int col = jg + 64 * p;

        unsigned wp[128];
        LOAD_WP4(W1, 0, p, jg)
        const float bj = b1v[col];

        for (int chunk = parity; chunk < NCHUNK; chunk += 2) {
            while (rload(&flagL0[b * 16]) < (chunk + 1) * CHUNK)
                __builtin_amdgcn_s_sleep(1);
            ACQUIRE_FENCE();  // one inv per chunk
            const int tbase = chunk * CHUNK;
            const float* src = out + ((size_t)b * TT + tbase) * 256;  // h0 rows
            float* dst = xpA + ((size_t)b * TT + tbase) * 256;        // xproj1
            proj_rows<false>(src, dst, wp, bj, CHUNK, hb, tid, p, jg, col);
            __syncthreads();  // drain vmcnt (dst stores) before release
            if (tid == 0) astore(&chunkdone[b * NCHUNK + chunk], 1);
        }
    }
    // all other bids: exit immediately (placement spacers)
}

extern "C" void kernel_launch(void* const* d_in, const int* in_sizes, int n_in,
                              void* d_out, int out_size, void* d_ws, size_t ws_size,
                              hipStream_t stream) {
    const float* x  = (const float*)d_in[0];  // [B,T,256]
    const float* h0 = (const float*)d_in[1];  // [2,B,256]
    const float* W0 = (const float*)d_in[2];  // [512,256]
    const float* b0 = (const float*)d_in[3];  // [256]
    const float* W1 = (const float*)d_in[4];  // [512,256]
    const float* b1 = (const float*)d_in[5];  // [256]
    float* out = (float*)d_out;               // [B*T*256] + [B*256]

    const size_t XPA_FLOATS = (size_t)BB * TT * 256;  // 64 MB
    const size_t FLAG_INTS = (size_t)BB * 16 + (size_t)BB * NCHUNK;
    const size_t NEEDED = XPA_FLOATS * 4 + FLAG_INTS * 4;

    if (ws_size >= NEEDED) {
        float* xpA = (float*)d_ws;
        int* flags = (int*)((char*)d_ws + XPA_FLOATS * 4);
        hipMemsetAsync(flags, 0, FLAG_INTS * 4, stream);
        proj20_kernel<false><<<512, 256, 0, stream>>>(x, W0, b0, xpA, 128);
        mega20_kernel<<<512, 256, 0, stream>>>(W0, W1, b1, h0, xpA, out, flags);
    } else {
        proj20_kernel<true><<<512, 256, 0, stream>>>(x, W0, b0, out, 128);
        scan20_kernel<<<BB, 256, 0, stream>>>(W0, h0, out, nullptr);
        proj20_kernel<true><<<512, 256, 0, stream>>>(out, W1, b1, out, 128);
        scan20_kernel<<<BB, 256, 0, stream>>>(W1, h0 + BB * 256, out, out + XPA_FLOATS);
    }
}

// Round 21
// 1228.011 us; speedup vs baseline: 1.7619x; 1.1540x over previous
//
#include <hip/hip_runtime.h>

// RNN: B=32, T=2048, E=256, H=256, L=2, f32 in/out, f16 dot core.
// v21 = best-known recombination:
//   - mega: EXACT r17 structure (grid 128, launch_bounds(256,1)):
//       bid 0-31  L0 scan -> d_out; publish flagL0[b] every CHUNK steps
//       bid 32-95 chasers (2/batch): xproj1 = h0 @ W1x + b1 -> ws.A
//       bid 96-127 L1 scan: wait chunkdone -> d_out + final ht
//     (r18 TLP, r19 ILP, r20 CU-pairing all REGRESSED vs this: the scan step
//      is LDS-pipe + dependency bound, not fillable idle time.)
//   - proj0: r18/r20-measured fast variant (512 blocks x 128 rows, non-alias
//     LDS-only per-row barrier): ~105us vs r17's 168us.
// Core (r17-proven): thread (jg=tid>>2, p=tid&3) partials 4 cols {jg+64c}
// over i-quarter [64p,64p+64): 8 ds_read_b128, 128 fdot2, 2 DPP quad
// butterflies/col, static col select. LDS f16 quarter-stride-144B.
// Weights: 128 packed f16x2 VGPRs (full unroll + unsigned + KEEPALIVE —
// r15/r16 lessons: partial unroll => scratch; KEEPALIVE => no AGPR parking).
// Sync (r13-proven): publisher __syncthreads + release store; consumer
// RELAXED poll + one acquire fence per chunk. Scan barrier LDS-only.

typedef _Float16 half2_t __attribute__((ext_vector_type(2)));

#define TT 2048
#define BB 32
#define XPB 8
#define CHUNK 64
#define NCHUNK (TT / CHUNK)  // 32

__device__ __forceinline__ unsigned packw(float lo, float hi) {
    half2_t r;
    r.x = (_Float16)lo;
    r.y = (_Float16)hi;
    return __builtin_bit_cast(unsigned, r);
}
#define H2(X) __builtin_bit_cast(half2_t, (X))

#define LDS_BARRIER() asm volatile("s_waitcnt lgkmcnt(0)\n\ts_barrier" ::: "memory")

__device__ __forceinline__ int rload(int* pf) {
    return __hip_atomic_load(pf, __ATOMIC_RELAXED, __HIP_MEMORY_SCOPE_AGENT);
}
__device__ __forceinline__ void astore(int* pf, int v) {
    __hip_atomic_store(pf, v, __ATOMIC_RELEASE, __HIP_MEMORY_SCOPE_AGENT);
}
#define ACQUIRE_FENCE() __builtin_amdgcn_fence(__ATOMIC_ACQUIRE, "agent")

// r13/r16-proven keep-alive: pin the 128 packed weights in arch VGPRs
#define KAW8(B)                                                             \
    "+v"(wp[(B)]), "+v"(wp[(B) + 1]), "+v"(wp[(B) + 2]), "+v"(wp[(B) + 3]), \
    "+v"(wp[(B) + 4]), "+v"(wp[(B) + 5]), "+v"(wp[(B) + 6]), "+v"(wp[(B) + 7])
#define KEEPALIVE()                                                  \
    asm volatile("" : KAW8(0), KAW8(8), KAW8(16), KAW8(24));         \
    asm volatile("" : KAW8(32), KAW8(40), KAW8(48), KAW8(56));       \
    asm volatile("" : KAW8(64), KAW8(72), KAW8(80), KAW8(88));       \
    asm volatile("" : KAW8(96), KAW8(104), KAW8(112), KAW8(120));

#define FDOT(H, W_, A) A = __builtin_amdgcn_fdot2(H2(H), H2(W_), A, false)
#define FD4(H, K)               \
    FDOT(H, wp[(K)], ac0);      \
    FDOT(H, wp[32 + (K)], ac1); \
    FDOT(H, wp[64 + (K)], ac2); \
    FDOT(H, wp[96 + (K)], ac3);

// partial dot over this lane's i-quarter for its 4 columns.
#define DOTS()                                                          \
    float ac0 = 0.f, ac1 = 0.f, ac2 = 0.f, ac3 = 0.f;                   \
    {                                                                   \
        const uint4* hp_ = hbq + 9 * p;                                 \
        uint4 q0 = hp_[0], q1 = hp_[1], q2 = hp_[2], q3 = hp_[3];       \
        uint4 q4 = hp_[4], q5 = hp_[5], q6 = hp_[6], q7 = hp_[7];       \
        FD4(q0.x, 0)  FD4(q0.y, 1)  FD4(q0.z, 2)  FD4(q0.w, 3)         \
        FD4(q1.x, 4)  FD4(q1.y, 5)  FD4(q1.z, 6)  FD4(q1.w, 7)         \
        FD4(q2.x, 8)  FD4(q2.y, 9)  FD4(q2.z, 10) FD4(q2.w, 11)        \
        FD4(q3.x, 12) FD4(q3.y, 13) FD4(q3.z, 14) FD4(q3.w, 15)        \
        FD4(q4.x, 16) FD4(q4.y, 17) FD4(q4.z, 18) FD4(q4.w, 19)        \
        FD4(q5.x, 20) FD4(q5.y, 21) FD4(q5.z, 22) FD4(q5.w, 23)        \
        FD4(q6.x, 24) FD4(q6.y, 25) FD4(q6.z, 26) FD4(q6.w, 27)        \
        FD4(q7.x, 28) FD4(q7.y, 29) FD4(q7.z, 30) FD4(q7.w, 31)        \
    }

// quad butterfly: x = sum over the 4 quad lanes (register-only, exact)
#define BFLY(x)                                                              \
    asm("v_add_f32_dpp %0, %0, %0 quad_perm:[1,0,3,2] row_mask:0xf "         \
        "bank_mask:0xf"                                                      \
        : "+v"(x));                                                          \
    asm("v_add_f32_dpp %0, %0, %0 quad_perm:[2,3,0,1] row_mask:0xf "         \
        "bank_mask:0xf"                                                      \
        : "+v"(x));

// load 128 packed weights (FULL unroll — r15 scratch lesson)
#define LOAD_WP4(Wm, rowbase, p_, jg_)                                       \
    _Pragma("unroll")                                                        \
    for (int c = 0; c < 4; ++c) {                                            \
        _Pragma("unroll")                                                    \
        for (int k = 0; k < 32; ++k) {                                       \
            const int col_ = (jg_) + 64 * c;                                 \
            wp[c * 32 + k] =                                                 \
                packw((Wm)[(size_t)((rowbase) + 64 * (p_) + 2 * k) * 256 +   \
                           col_],                                            \
                      (Wm)[(size_t)((rowbase) + 64 * (p_) + 2 * k + 1) * 256 \
                           + col_]);                                         \
        }                                                                    \
    }

// f16 staging index for element i (quarter stride 72 f16 = 144 B)
__device__ __forceinline__ int sidx_of(int i) {
    return 72 * (i >> 6) + (i & 63);
}

// proj rows: dst[r][col] = src[r][:] . W[:256][col] + b[col]
// ALIAS=true: in-place path, per-row full __syncthreads (vmcnt drain).
// ALIAS=false: distinct src/dst, LDS-only barrier per row.
template <bool ALIAS>
__device__ __forceinline__ void proj_rows(
    const float* __restrict__ src, float* __restrict__ dst,
    unsigned (&wp)[128], float bj, int nrows, uint4 (*hb)[36], int tid,
    int p, int jg, int col)
{
    _Float16* st0 = reinterpret_cast<_Float16*>(hb[0]);
    _Float16* st1 = reinterpret_cast<_Float16*>(hb[1]);
    const int si = sidx_of(tid);
    st0[si] = (_Float16)src[tid];
    __syncthreads();
    for (int r = 0; r < nrows; ++r) {
        KEEPALIVE()
        _Float16* stn = (r & 1) ? st0 : st1;
        if (r + 1 < nrows) stn[si] = (_Float16)src[(size_t)(r + 1) * 256 + tid];
        const uint4* hbq = hb[r & 1];
        DOTS()
        BFLY(ac0) BFLY(ac1) BFLY(ac2) BFLY(ac3)
        float z = (p == 0) ? ac0 : ((p == 1) ? ac1 : ((p == 2) ? ac2 : ac3));
        dst[(size_t)r * 256 + col] = z + bj;
        if (ALIAS) __syncthreads();
        else LDS_BARRIER();
    }
}

// MODE: 0 = serial, 1 = L0 (publish pubflag), 2 = L1 (wait waitflags)
template <int MODE>
__device__ __forceinline__ void scan_core(
    const float* __restrict__ W, const float* __restrict__ h_init,
    const float* __restrict__ xsrc, float* __restrict__ hdst, float* hfinal,
    int* pubflag, int* waitflags, uint4 (*hb)[36], int tid)
{
    const int p = tid & 3;
    const int jg = tid >> 2;
    const int col = jg + 64 * p;

    unsigned wp[128];
    LOAD_WP4(W, 256, p, jg)

    _Float16* hw0 = reinterpret_cast<_Float16*>(hb[0]);
    _Float16* hw1 = reinterpret_cast<_Float16*>(hb[1]);
    hw0[sidx_of(tid)] = (_Float16)h_init[tid];
    const int wsi = 72 * p + jg;  // where this lane's column lives

    float xpc[XPB], xpn[XPB], hs[XPB];

    auto step = [&](int t, float xp) -> float {
        KEEPALIVE()
        const uint4* hbq = hb[t & 1];
        DOTS()
        BFLY(ac0) BFLY(ac1) BFLY(ac2) BFLY(ac3)
        float z = (p == 0) ? ac0 : ((p == 1) ? ac1 : ((p == 2) ? ac2 : ac3));
        z += xp;
        const float e = __expf(2.0f * z);
        const float hn = 1.0f - 2.0f / (e + 1.0f);
        _Float16* dstw = ((t + 1) & 1) ? hw1 : hw0;
        dstw[wsi] = (_Float16)hn;
        LDS_BARRIER();
        return hn;
    };

    if (MODE != 2) {
#pragma unroll
        for (int u = 0; u < XPB; ++u) xpc[u] = xsrc[(size_t)u * 256 + col];
        __syncthreads();
        for (int t0 = 0; t0 < TT; t0 += XPB) {
            const bool more = (t0 + XPB) < TT;
            if (more) {
#pragma unroll
                for (int u = 0; u < XPB; ++u)
                    xpn[u] = xsrc[(size_t)(t0 + XPB + u) * 256 + col];
            }
#pragma unroll
            for (int u = 0; u < XPB; ++u) hs[u] = step(t0 + u, xpc[u]);
#pragma unroll
            for (int u = 0; u < XPB; ++u)
                hdst[(size_t)(t0 + u) * 256 + col] = hs[u];
            if (MODE == 1 && (((t0 + XPB) & (CHUNK - 1)) == 0)) {
                __syncthreads();  // drain vmcnt (h stores) before release
                if (tid == 0) astore(pubflag, t0 + XPB);
            }
            if (more) {
#pragma unroll
                for (int u = 0; u < XPB; ++u) xpc[u] = xpn[u];
            }
        }
        if (MODE == 0 && hfinal != nullptr) hfinal[col] = hs[XPB - 1];
    } else {
        __syncthreads();
        for (int chunk = 0; chunk < NCHUNK; ++chunk) {
            const int tbase = chunk * CHUNK;
            while (rload(&waitflags[chunk]) == 0) __builtin_amdgcn_s_sleep(1);
            ACQUIRE_FENCE();  // one inv per chunk
#pragma unroll
            for (int u = 0; u < XPB; ++u)
                xpc[u] = xsrc[(size_t)(tbase + u) * 256 + col];
            for (int g = 0; g < CHUNK / XPB; ++g) {
                const int t0 = tbase + g * XPB;
                if (g + 1 < CHUNK / XPB) {
#pragma unroll
                    for (int u = 0; u < XPB; ++u)
                        xpn[u] = xsrc[(size_t)(t0 + XPB + u) * 256 + col];
                }
#pragma unroll
                for (int u = 0; u < XPB; ++u) hs[u] = step(t0 + u, xpc[u]);
#pragma unroll
                for (int u = 0; u < XPB; ++u)
                    hdst[(size_t)(t0 + u) * 256 + col] = hs[u];
                if (t0 + XPB == TT) hfinal[col] = hs[XPB - 1];
                if (g + 1 < CHUNK / XPB) {
#pragma unroll
                    for (int u = 0; u < XPB; ++u) xpc[u] = xpn[u];
                }
            }
        }
    }
}

// standalone proj
template <bool ALIAS>
__global__ __launch_bounds__(256, 1) void proj21_kernel(
    const float* in, const float* __restrict__ W, const float* __restrict__ bias,
    float* out, int rows_per_wg)
{
    __shared__ uint4 hb[2][36];
    const int tid = threadIdx.x;
    const int p = tid & 3;
    const int jg = tid >> 2;
    const int col = jg + 64 * p;
    unsigned wp[128];
    LOAD_WP4(W, 0, p, jg)
    const float bj = bias[col];
    const size_t r0 = (size_t)blockIdx.x * rows_per_wg;
    proj_rows<ALIAS>(in + r0 * 256, out + r0 * 256, wp, bj, rows_per_wg, hb,
                     tid, p, jg, col);
}

// serial fallback scan (single batch, 256 thr)
__global__ __launch_bounds__(256, 1) void scan21_kernel(
    const float* __restrict__ W, const float* __restrict__ h_init,
    float* __restrict__ io, float* __restrict__ hfinal)
{
    __shared__ uint4 hb[2][36];
    const int b = blockIdx.x;
    scan_core<0>(W, h_init + b * 256, io + (size_t)b * TT * 256,
                 io + (size_t)b * TT * 256,
                 hfinal ? hfinal + b * 256 : nullptr, nullptr, nullptr, hb,
                 threadIdx.x);
}

// mega: EXACT r17 layout — grid 128 x 256 thr.
__global__ __launch_bounds__(256, 1) void mega21_kernel(
    const float* __restrict__ W0, const float* __restrict__ W1,
    const float* __restrict__ b1v, const float* __restrict__ h0init,
    float* xpA, float* out, int* flags)
{
    __shared__ uint4 hb[2][36];
    const int tid = threadIdx.x;
    const int bid = blockIdx.x;
    int* flagL0 = flags;               // stride 16 ints per batch (64B line)
    int* chunkdone = flags + BB * 16;  // stride NCHUNK ints per batch

    if (bid < BB) {
        const int b = bid;
        scan_core<1>(W0, h0init + b * 256, xpA + (size_t)b * TT * 256,
                     out + (size_t)b * TT * 256, nullptr, &flagL0[b * 16],
                     nullptr, hb, tid);
    } else if (bid >= 3 * BB) {
        const int b = bid - 3 * BB;
        scan_core<2>(W1, h0init + (size_t)(BB + b) * 256,
                     xpA + (size_t)b * TT * 256, out + (size_t)b * TT * 256,
                     out + (size_t)BB * TT * 256 + b * 256, nullptr,
                     &chunkdone[b * NCHUNK], hb, tid);
    } else {
        // ---- proj1 chasers (2 per batch) ----
        const int k = bid - BB;  // 0..63
        const int b = k >> 1;
        const int half = k & 1;
        const int p = tid & 3;
        const int jg = tid >> 2;
        const int col = jg + 64 * p;

        unsigned wp[128];
        LOAD_WP4(W1, 0, p, jg)
        const float bj = b1v[col];

        for (int chunk = half; chunk < NCHUNK; chunk += 2) {
            while (rload(&flagL0[b * 16]) < (chunk + 1) * CHUNK)
                __builtin_amdgcn_s_sleep(1);
            ACQUIRE_FENCE();  // one inv per chunk
            const int tbase = chunk * CHUNK;
            const float* src = out + ((size_t)b * TT + tbase) * 256;  // h0 rows
            float* dst = xpA + ((size_t)b * TT + tbase) * 256;        // xproj1
            proj_rows<false>(src, dst, wp, bj, CHUNK, hb, tid, p, jg, col);
            __syncthreads();  // drain vmcnt (dst stores) before release
            if (tid == 0) astore(&chunkdone[b * NCHUNK + chunk], 1);
        }
    }
}

extern "C" void kernel_launch(void* const* d_in, const int* in_sizes, int n_in,
                              void* d_out, int out_size, void* d_ws, size_t ws_size,
                              hipStream_t stream) {
    const float* x  = (const float*)d_in[0];  // [B,T,256]
    const float* h0 = (const float*)d_in[1];  // [2,B,256]
    const float* W0 = (const float*)d_in[2];  // [512,256]
    const float* b0 = (const float*)d_in[3];  // [256]
    const float* W1 = (const float*)d_in[4];  // [512,256]
    const float* b1 = (const float*)d_in[5];  // [256]
    float* out = (float*)d_out;               // [B*T*256] + [B*256]

    const size_t XPA_FLOATS = (size_t)BB * TT * 256;  // 64 MB
    const size_t FLAG_INTS = (size_t)BB * 16 + (size_t)BB * NCHUNK;
    const size_t NEEDED = XPA_FLOATS * 4 + FLAG_INTS * 4;

    if (ws_size >= NEEDED) {
        float* xpA = (float*)d_ws;
        int* flags = (int*)((char*)d_ws + XPA_FLOATS * 4);
        hipMemsetAsync(flags, 0, FLAG_INTS * 4, stream);
        proj21_kernel<false><<<512, 256, 0, stream>>>(x, W0, b0, xpA, 128);
        mega21_kernel<<<4 * BB, 256, 0, stream>>>(W0, W1, b1, h0, xpA, out, flags);
    } else {
        proj21_kernel<true><<<512, 256, 0, stream>>>(x, W0, b0, out, 128);
        scan21_kernel<<<BB, 256, 0, stream>>>(W0, h0, out, nullptr);
        proj21_kernel<true><<<512, 256, 0, stream>>>(out, W1, b1, out, 128);
        scan21_kernel<<<BB, 256, 0, stream>>>(W1, h0 + BB * 256, out, out + XPA_FLOATS);
    }
}